// Round 9
// baseline (81.528 us; speedup 1.0000x reference)
//
#include <hip/hip_runtime.h>

// v9: two-kernel MFMA restructure.
// Insight: CRZ ring + 56 CRX gates depend only on `weights` -> fixed 256x256
// unitary V shared across the whole batch. Encoding layer gives a per-batch
// PRODUCT state psi_b. out[b,q] = sum_idx sign_q(idx) |(V psi_b)[idx]|^2.
// Kernel 1: build V by running the verified v5 circuit body on 256 basis
//   columns (CRZ phase folded in), store as f16 in d_ws, pre-swizzled into
//   mfma_f32_16x16x32_f16 B-fragment order.
// Kernel 2: per block: 32 batch rows; build psi (f16) in LDS; complex GEMM
//   via MFMA (Cr += Ar*Br + Ai*(-Bi); Ci += Ar*Bi + Ai*Br), fused epilogue:
//   P = Cr^2+Ci^2, tile-signs for qubits 0..3, DPP col-butterfly for 4..7.

typedef _Float16 half_t;
typedef __attribute__((ext_vector_type(8))) _Float16 half8;
typedef __attribute__((ext_vector_type(4))) float float4v;

static __device__ __forceinline__ float rlane(float v, int src) {
    return __int_as_float(__builtin_amdgcn_readlane(__float_as_int(v), src));
}
template <int CTRL>
static __device__ __forceinline__ float dppf(float x) {
    return __int_as_float(__builtin_amdgcn_update_dpp(0, __float_as_int(x), CTRL, 0xF, 0xF, true));
}
static __device__ __forceinline__ float xor1f(float x) { return dppf<0xB1>(x); }
static __device__ __forceinline__ float xor2f(float x) { return dppf<0x4E>(x); }
static __device__ __forceinline__ float xor4f(float x) { return dppf<0x1B>(dppf<0x141>(x)); }
static __device__ __forceinline__ float xor8f(float x) { return dppf<0x128>(x); }
static __device__ __forceinline__ float xorMf(float x, int m) {
    if (m == 1) return xor1f(x);
    if (m == 2) return xor2f(x);
    if (m == 4) return xor4f(x);
    return xor8f(x);
}
static __device__ __forceinline__ float2 xorM2(float2 a, int m) {
    float2 t; t.x = xorMf(a.x, m); t.y = xorMf(a.y, m); return t;
}
static __device__ __forceinline__ float2 cmul(float2 a, float2 b) {
    float2 t;
    t.x = a.x * b.x - a.y * b.y;
    t.y = a.x * b.y + a.y * b.x;
    return t;
}
static __device__ __forceinline__ float2 rotA(float2 t, float2 u, float c, float s) {
    float2 d;
    d.x = c * t.x + s * u.y;
    d.y = c * t.y - s * u.x;
    return d;
}

// ---------------- Kernel 1: build V (verified v5 body on basis columns) ----
__global__ __launch_bounds__(256, 4) void buildV_kernel(const float* __restrict__ W,
                                                        half_t* __restrict__ Vr,
                                                        half_t* __restrict__ Vi) {
    const int lane = threadIdx.x & 63;
    const int g = lane >> 4;
    const int s = lane & 15;
    const int eid = (blockIdx.x * 4 + (threadIdx.x >> 6)) * 4 + g;  // column k

    // CRX trig (wave-shared)
    float gcv = 1.0f, gsv = 0.0f;
    if (lane < 56) {
        const int i = lane / 7;
        const int jj = lane - 7 * i;
        const int j = jj + (jj >= i ? 1 : 0);
        const float h = 0.5f * W[(1 + i) * 72 + j];
        __sincosf(h, &gsv, &gcv);
    }

    // basis state e_eid in L1 (idx = r*16 + s)
    float2 a[16];
#pragma unroll
    for (int r = 0; r < 16; ++r) {
        a[r].x = (s == (eid & 15) && r == (eid >> 4)) ? 1.0f : 0.0f;
        a[r].y = 0.0f;
    }

    // CRZ ring fused diagonal (L1 mapping) — verbatim from v5
    {
        const float wv0 = W[0], wv1 = W[1], wv2 = W[2], wv3 = W[3];
        const float wv4 = W[4], wv5 = W[5], wv6 = W[6], wv7 = W[7];
        const int s3 = (s >> 3) & 1, s2 = (s >> 2) & 1, s1 = (s >> 1) & 1, s0 = s & 1;
        float phiS = 0.0f;
        phiS += s3 ? (s2 ? wv4 : -wv4) : 0.0f;
        phiS += s2 ? (s1 ? wv5 : -wv5) : 0.0f;
        phiS += s1 ? (s0 ? wv6 : -wv6) : 0.0f;
        const float termA = s3 ? wv3 : -wv3;
        const float termB = s0 ? wv7 : 0.0f;
#pragma unroll
        for (int r = 0; r < 16; ++r) {
            const int b3 = (r >> 3) & 1, b2 = (r >> 2) & 1, b1 = (r >> 1) & 1, b0 = r & 1;
            float phi = phiS + (b3 ? termB : -termB);
            if (b3) phi += b2 ? wv0 : -wv0;
            if (b2) phi += b1 ? wv1 : -wv1;
            if (b1) phi += b0 ? wv2 : -wv2;
            if (b0) phi += termA;
            float2 ph;
            __sincosf(0.5f * phi, &ph.y, &ph.x);
            a[r] = cmul(a[r], ph);
        }
    }

    // CRX phase A: groups i=0..3 in L1 (ctrl = reg bit 3-i) — verbatim
#pragma unroll
    for (int i = 0; i < 4; ++i) {
        float cg[8], sg[8];
#pragma unroll
        for (int j = 0; j < 8; ++j) {
            if (j == i) continue;
            const int gi = i * 7 + (j < i ? j : j - 1);
            cg[j] = rlane(gcv, gi);
            sg[j] = rlane(gsv, gi);
        }
        const int rc = 3 - i;
#pragma unroll
        for (int j = 0; j < 8; ++j) {
            if (j == i) continue;
            if (j < 4) {
                const int mt = 1 << (3 - j);
#pragma unroll
                for (int r = 0; r < 16; ++r) {
                    if (!((r >> rc) & 1)) continue;
                    if (r & mt) continue;
                    const int rp = r | mt;
                    const float2 t = a[r], u = a[rp];
                    a[r]  = rotA(t, u, cg[j], sg[j]);
                    a[rp] = rotA(u, t, cg[j], sg[j]);
                }
            } else {
                const int ms = 1 << (7 - j);
#pragma unroll
                for (int r = 0; r < 16; ++r) {
                    if (!((r >> rc) & 1)) continue;
                    const float2 p = xorM2(a[r], ms);
                    a[r] = rotA(a[r], p, cg[j], sg[j]);
                }
            }
        }
    }

    // 16x16 transpose L1 -> L2 — verbatim
#pragma unroll
    for (int k = 1; k <= 8; k <<= 1) {
        const bool sk = (s & k) != 0;
#pragma unroll
        for (int r = 0; r < 16; ++r) {
            if (r & k) continue;
            const int rp = r | k;
            const float2 tp = xorM2(a[rp], k);
            const float2 tr = xorM2(a[r],  k);
            a[r].x  = sk ? tp.x : a[r].x;
            a[r].y  = sk ? tp.y : a[r].y;
            a[rp].x = sk ? a[rp].x : tr.x;
            a[rp].y = sk ? a[rp].y : tr.y;
        }
    }

    // CRX phase B: groups i=4..7 in L2 (ctrl = reg bit 7-i) — verbatim
#pragma unroll
    for (int i = 4; i < 8; ++i) {
        float cg[8], sg[8];
#pragma unroll
        for (int j = 0; j < 8; ++j) {
            if (j == i) continue;
            const int gi = i * 7 + (j < i ? j : j - 1);
            cg[j] = rlane(gcv, gi);
            sg[j] = rlane(gsv, gi);
        }
        const int rc = 7 - i;
#pragma unroll
        for (int j = 0; j < 8; ++j) {
            if (j == i) continue;
            if (j < 4) {
                const int ms = 1 << (3 - j);
#pragma unroll
                for (int r = 0; r < 16; ++r) {
                    if (!((r >> rc) & 1)) continue;
                    const float2 p = xorM2(a[r], ms);
                    a[r] = rotA(a[r], p, cg[j], sg[j]);
                }
            } else {
                const int mt = 1 << (7 - j);
#pragma unroll
                for (int r = 0; r < 16; ++r) {
                    if (!((r >> rc) & 1)) continue;
                    if (r & mt) continue;
                    const int rp = r | mt;
                    const float2 t = a[r], u = a[rp];
                    a[r]  = rotA(t, u, cg[j], sg[j]);
                    a[rp] = rotA(u, t, cg[j], sg[j]);
                }
            }
        }
    }

    // store column eid: lane s holds V[idx = s*16 + r][eid] (L2 layout).
    // B-frag order for tile T=s, k-step ks: element (kq,n,j) at
    // ((T*8+ks)*64 + kq*16 + n)*8 + j  with k = ks*32 + kq*8 + j, n = r.
    const int ks = eid >> 5, kq = (eid >> 3) & 3, jj = eid & 7;
#pragma unroll
    for (int r = 0; r < 16; ++r) {
        const int off = ((s * 8 + ks) * 64 + kq * 16 + r) * 8 + jj;
        Vr[off] = (half_t)a[r].x;
        Vi[off] = (half_t)a[r].y;
    }
}

// ---------------- Kernel 2: psi build + complex MFMA GEMM + fused epilogue --
#define PSI_STRIDE 264   // 256 + 8 f16 pad (keeps 16B alignment, breaks bank stride)

__global__ __launch_bounds__(256, 2) void gemm_kernel(const float* __restrict__ X,
                                                      const half_t* __restrict__ Vr,
                                                      const half_t* __restrict__ Vi,
                                                      float* __restrict__ out,
                                                      int B) {
    __shared__ float4 u_lds[32][8];
    __shared__ half_t psir[32][PSI_STRIDE];
    __shared__ half_t psii[32][PSI_STRIDE];
    __shared__ float part[32][8][4];

    const int tid = threadIdx.x;
    const int rowbase = blockIdx.x * 32;

    // phase 1: per (row m, qubit q) fused H->RZ->RY columns (sqrt2-scaled)
    {
        const int m = tid >> 3, q = tid & 7;
        int row = rowbase + m; if (row >= B) row = B - 1;
        const float2 xq = ((const float2*)X)[row * 8 + q];
        float cz, sz, cy, sy;
        __sincosf(0.5f * xq.x, &sz, &cz);
        __sincosf(0.5f * xq.y, &sy, &cy);
        float4 u;
        u.x = (cy - sy) * cz;  u.y = -(cy + sy) * sz;   // u[0]
        u.z = (cy + sy) * cz;  u.w = (cy - sy) * sz;    // u[1]
        u_lds[m][q] = u;
    }
    __syncthreads();

    // phase 2: build psi[m][k] = prod_q u_q[bit_{7-q}(k)], k = kh*32 + kl
    {
        const int m = tid >> 3, kh = tid & 7;
        float2 uu[8][2];
#pragma unroll
        for (int q = 0; q < 8; ++q) {
            const float4 u = u_lds[m][q];
            uu[q][0].x = u.x; uu[q][0].y = u.y;
            uu[q][1].x = u.z; uu[q][1].y = u.w;
        }
        const float2 pre = cmul(cmul(uu[0][(kh >> 2) & 1], uu[1][(kh >> 1) & 1]), uu[2][kh & 1]);
        float2 t1[2], t2[4], t3[8], t4[16];
        t1[0] = cmul(pre, uu[3][0]);  t1[1] = cmul(pre, uu[3][1]);
#pragma unroll
        for (int h = 0; h < 2; ++h) { t2[2*h] = cmul(t1[h], uu[4][0]); t2[2*h+1] = cmul(t1[h], uu[4][1]); }
#pragma unroll
        for (int h = 0; h < 4; ++h) { t3[2*h] = cmul(t2[h], uu[5][0]); t3[2*h+1] = cmul(t2[h], uu[5][1]); }
#pragma unroll
        for (int h = 0; h < 8; ++h) { t4[2*h] = cmul(t3[h], uu[6][0]); t4[2*h+1] = cmul(t3[h], uu[6][1]); }
        unsigned int* pr = (unsigned int*)&psir[m][kh * 32];
        unsigned int* pi = (unsigned int*)&psii[m][kh * 32];
#pragma unroll
        for (int h = 0; h < 16; ++h) {
            const float2 v0 = cmul(t4[h], uu[7][0]);
            const float2 v1 = cmul(t4[h], uu[7][1]);
            union { half_t h2[2]; unsigned int u; } cr, ci;
            cr.h2[0] = (half_t)v0.x; cr.h2[1] = (half_t)v1.x;
            ci.h2[0] = (half_t)v0.y; ci.h2[1] = (half_t)v1.y;
            pr[h] = cr.u; pi[h] = ci.u;
        }
    }
    __syncthreads();

    // GEMM: wave w handles n-tiles T = w*4..w*4+3 (64 idx), 2 row-tiles of 16
    const int w = tid >> 6;
    const int lane = tid & 63;
    const int m16 = lane & 15;
    float4v Cr[2][4], Ci[2][4];
#pragma unroll
    for (int rt = 0; rt < 2; ++rt)
#pragma unroll
        for (int t = 0; t < 4; ++t) {
            Cr[rt][t] = (float4v){0.f, 0.f, 0.f, 0.f};
            Ci[rt][t] = (float4v){0.f, 0.f, 0.f, 0.f};
        }
#pragma unroll
    for (int ks = 0; ks < 8; ++ks) {
        const int koff = ks * 32 + (lane >> 4) * 8;
        const half8 Ar0 = *(const half8*)&psir[m16][koff];
        const half8 Ai0 = *(const half8*)&psii[m16][koff];
        const half8 Ar1 = *(const half8*)&psir[16 + m16][koff];
        const half8 Ai1 = *(const half8*)&psii[16 + m16][koff];
#pragma unroll
        for (int t = 0; t < 4; ++t) {
            const int T = w * 4 + t;
            const int boff = ((T * 8 + ks) * 64 + lane) * 8;
            const half8 Br = *(const half8*)(Vr + boff);
            const half8 Bi = *(const half8*)(Vi + boff);
            const half8 Bin = -Bi;
            Cr[0][t] = __builtin_amdgcn_mfma_f32_16x16x32_f16(Ar0, Br,  Cr[0][t], 0, 0, 0);
            Cr[0][t] = __builtin_amdgcn_mfma_f32_16x16x32_f16(Ai0, Bin, Cr[0][t], 0, 0, 0);
            Ci[0][t] = __builtin_amdgcn_mfma_f32_16x16x32_f16(Ar0, Bi,  Ci[0][t], 0, 0, 0);
            Ci[0][t] = __builtin_amdgcn_mfma_f32_16x16x32_f16(Ai0, Br,  Ci[0][t], 0, 0, 0);
            Cr[1][t] = __builtin_amdgcn_mfma_f32_16x16x32_f16(Ar1, Br,  Cr[1][t], 0, 0, 0);
            Cr[1][t] = __builtin_amdgcn_mfma_f32_16x16x32_f16(Ai1, Bin, Cr[1][t], 0, 0, 0);
            Ci[1][t] = __builtin_amdgcn_mfma_f32_16x16x32_f16(Ar1, Bi,  Ci[1][t], 0, 0, 0);
            Ci[1][t] = __builtin_amdgcn_mfma_f32_16x16x32_f16(Ai1, Br,  Ci[1][t], 0, 0, 0);
        }
    }

    // epilogue: P = Cr^2 + Ci^2 ; qubits 0..3 from tile signs, 4..7 from col butterfly
    const float sw0 = ((w >> 1) & 1) ? -1.0f : 1.0f;   // qubit0 sign (idx bit7)
    const float sw1 = (w & 1) ? -1.0f : 1.0f;          // qubit1 sign (idx bit6)
    const int quad = lane >> 4;
#pragma unroll
    for (int rt = 0; rt < 2; ++rt) {
        float A0[4] = {0.f, 0.f, 0.f, 0.f};
        float A2[4] = {0.f, 0.f, 0.f, 0.f};
        float A3[4] = {0.f, 0.f, 0.f, 0.f};
#pragma unroll
        for (int t = 0; t < 4; ++t) {
            const int T = w * 4 + t;
            const float s2 = ((T >> 1) & 1) ? -1.0f : 1.0f;  // qubit2 (idx bit5)
            const float s3 = (T & 1) ? -1.0f : 1.0f;         // qubit3 (idx bit4)
#pragma unroll
            for (int reg = 0; reg < 4; ++reg) {
                const float cr = Cr[rt][t][reg], ci = Ci[rt][t][reg];
                const float P = cr * cr + ci * ci;
                A0[reg] += P;
                A2[reg] += s2 * P;
                A3[reg] += s3 * P;
            }
        }
#pragma unroll
        for (int reg = 0; reg < 4; ++reg) {
            float Z = A0[reg], E7, E6, E5, E4;
            { const float tt = xor1f(Z); E7 = Z - tt; Z += tt; }
            { const float tt = xor2f(Z); E6 = Z - tt; Z += tt; E7 += xor2f(E7); }
            { const float tt = xor4f(Z); E5 = Z - tt; Z += tt; E7 += xor4f(E7); E6 += xor4f(E6); }
            { const float tt = xor8f(Z); E4 = Z - tt; Z += tt; E7 += xor8f(E7); E6 += xor8f(E6); E5 += xor8f(E5); }
            float Q2 = A2[reg]; Q2 += xor1f(Q2); Q2 += xor2f(Q2); Q2 += xor4f(Q2); Q2 += xor8f(Q2);
            float Q3 = A3[reg]; Q3 += xor1f(Q3); Q3 += xor2f(Q3); Q3 += xor4f(Q3); Q3 += xor8f(Q3);
            if (m16 == 0) {
                const int m = rt * 16 + quad * 4 + reg;
                part[m][0][w] = sw0 * Z;
                part[m][1][w] = sw1 * Z;
                part[m][2][w] = Q2;
                part[m][3][w] = Q3;
                part[m][4][w] = E4;
                part[m][5][w] = E5;
                part[m][6][w] = E6;
                part[m][7][w] = E7;
            }
        }
    }
    __syncthreads();
    {
        const int m = tid >> 3, q = tid & 7;
        const int row = rowbase + m;
        if (row < B) {
            const float v = part[m][q][0] + part[m][q][1] + part[m][q][2] + part[m][q][3];
            out[row * 8 + q] = v * (1.0f / 256.0f);
        }
    }
}

extern "C" void kernel_launch(void* const* d_in, const int* in_sizes, int n_in,
                              void* d_out, int out_size, void* d_ws, size_t ws_size,
                              hipStream_t stream) {
    const float* X = (const float*)d_in[0];
    const float* W = (const float*)d_in[1];
    float* out = (float*)d_out;
    const int B = in_sizes[0] / 16;
    half_t* Vr = (half_t*)d_ws;
    half_t* Vi = Vr + 256 * 256;
    buildV_kernel<<<16, 256, 0, stream>>>(W, Vr, Vi);
    gemm_kernel<<<(B + 31) / 32, 256, 0, stream>>>(X, Vr, Vi, out, B);
}